// Round 5
// baseline (119.556 us; speedup 1.0000x reference)
//
#include <hip/hip_runtime.h>
#include <hip/hip_fp16.h>
#include <math.h>
#include <stdint.h>

// SupConLossTopK, K=8192, D=256, 64 labels, T=0.1, MAX_POS=6, NEG_K=30.
// Round 15 = dispatch-count attack (8->7): k_gram+k_anchor fused into k_strip.
//  - k_prep : round-12 normalize+bucket, minus g_meta/g_soff (no consumers).
//  - k_strip: grid (64 buckets x 10 strips). Each block MFMA-computes its
//             strip's 32xBc sim rows into LDS (global-fed frags, r14-style)
//             then processes those 32 anchors in-place (r9 anchor body,
//             negatives' 16 row-chunks preloaded to regs for MLP depth 16).
//             No cross-block deps, no g_sims HBM round-trip, no g_meta.
//  - k_final: unchanged separate 1-block mean (r13 lesson: device-scope
//             arrive patterns cost ~33ns/arrival; 2048 arrivals = +52us).
// Rationale: r14 showed kernels sum to ~12us while the controllable slice is
// ~56us -> per-dispatch overhead (~6us x 7 boundaries) dominates; cut nodes.
// No same-address global atomics anywhere (r4+r13 lessons).
// Harness floor inside dur_us: ~44us 0xAA poison of 256MiB ws + restore +
// graph node gaps.
// exp(sim - rowmax) ratios == exp(sim) ratios -> no rowmax pass.

#define NEGK 30
#define MAXP 6
#define MAXBC 320   // max bucket rows (actual ~128 +-11; P(>320) ~ 1e-60)
#define SR 32       // strip rows (anchors per k_strip block)

typedef _Float16 h2v __attribute__((ext_vector_type(2)));
typedef _Float16 f16x8 __attribute__((ext_vector_type(8)));
typedef float f32x16 __attribute__((ext_vector_type(16)));

__device__ __forceinline__ uint64_t mix64(uint64_t z) {
  z += 0x9E3779B97F4A7C15ULL;
  z = (z ^ (z >> 30)) * 0xBF58476D1CE4E5B9ULL;
  z = (z ^ (z >> 27)) * 0x94D049BB133111EBULL;
  return z ^ (z >> 31);
}

__device__ __forceinline__ float wave_reduce_add(float p) {
#pragma unroll
  for (int o = 32; o; o >>= 1) p += __shfl_down(p, o, 64);
  return p;  // lane 0
}

// dot of 8 packed halfs (one 16B chunk) accumulated into acc
__device__ __forceinline__ float dot8h(uint4 a, uint4 b, float acc) {
  const h2v* pa = (const h2v*)&a;
  const h2v* pb = (const h2v*)&b;
#if __has_builtin(__builtin_amdgcn_fdot2)
#pragma unroll
  for (int q = 0; q < 4; ++q) acc = __builtin_amdgcn_fdot2(pa[q], pb[q], acc, false);
#else
#pragma unroll
  for (int q = 0; q < 4; ++q)
    acc += (float)pa[q].x * (float)pb[q].x + (float)pa[q].y * (float)pb[q].y;
#endif
  return acc;
}

// ---- fused: blocks 0..K/4-1 normalize rows -> fp16; block K/4 bucket sort --
__global__ __launch_bounds__(256) void k_prep(const float* __restrict__ F,
                                              const int* __restrict__ labels, int K,
                                              __half* __restrict__ Fh,
                                              int* __restrict__ g_start,
                                              int* __restrict__ g_bucket) {
  __shared__ int cnt[64], start[65], cur[64];
  const int tid = threadIdx.x;

  if ((int)blockIdx.x < K / 4) {
    const int row = blockIdx.x * 4 + (tid >> 6);
    const int lane = tid & 63;
    const float4 a = ((const float4*)(F + (size_t)row * 256))[lane];
    float p = a.x * a.x + a.y * a.y + a.z * a.z + a.w * a.w;
    p = wave_reduce_add(p);
    p = __shfl(p, 0, 64);
    const float inv = 1.0f / fmaxf(sqrtf(p), 1e-12f);
    union { __half2 h[2]; uint2 u; } cv;
    cv.h[0] = __float22half2_rn(make_float2(a.x * inv, a.y * inv));
    cv.h[1] = __float22half2_rn(make_float2(a.z * inv, a.w * inv));
    ((uint2*)(Fh + (size_t)row * 256))[lane] = cv.u;
    return;
  }

  // bucket block
  if (tid < 64) cnt[tid] = 0;
  __syncthreads();
  for (int t = tid; t < K; t += 256) atomicAdd(&cnt[labels[t] & 63], 1);
  __syncthreads();
  if (tid == 0) {
    int acc = 0;
    for (int l = 0; l < 64; ++l) { start[l] = acc; acc += cnt[l]; }
    start[64] = acc;
  }
  __syncthreads();
  if (tid < 64) cur[tid] = start[tid];
  if (tid < 65) g_start[tid] = start[tid];
  __syncthreads();
  for (int t = tid; t < K; t += 256) {
    const int l = labels[t] & 63;
    const int p = atomicAdd(&cur[l], 1);
    g_bucket[p] = t;
  }
}

// ---- fused strip kernel: 32xBc Gram rows (MFMA, global-fed) -> LDS, then
// per-anchor loss for those 32 anchors. Grid (64, 10). No cross-block deps.
__global__ __launch_bounds__(256, 2) void k_strip(
    const __half* __restrict__ Fh, const int* __restrict__ g_start,
    const int* __restrict__ g_bucket, float* __restrict__ g_part, int K) {
  __shared__ float sims[SR][MAXBC];   // 32 x 320 x 4B = 40KB
  __shared__ uint4 sAr[4 * 32];       // 4 waves x 512B anchor staging

  const int b  = blockIdx.x;
  const int bs = g_start[b];
  const int B  = g_start[b + 1] - bs;
  const int Bc = B < MAXBC ? B : MAXBC;
  if (Bc <= 0) return;
  const int r0 = blockIdx.y * SR;
  if (r0 >= Bc) return;

  const int tid = threadIdx.x;
  const int wv = tid >> 6, lane = tid & 63;
  const int kq = lane >> 5;             // 0/1 -> +8 halfs within 16-half K-step

  // ---- phase 1: strip Gram rows via MFMA (global-fed fragments) ----
  // A side (strip rows) hoisted into regs once per wave.
  {
    const int rA = r0 + (lane & 31);
    const int gA = g_bucket[bs + (rA < Bc ? rA : Bc - 1)];
    const uint4* pA = (const uint4*)(Fh + (size_t)gA * 256) + kq;
    uint4 afr[16];
#pragma unroll
    for (int it = 0; it < 16; ++it) afr[it] = pA[2 * it];

    for (int ct = wv; ct * 32 < Bc; ct += 4) {
      const int rB = ct * 32 + (lane & 31);
      const int gB = g_bucket[bs + (rB < Bc ? rB : Bc - 1)];
      const uint4* pB = (const uint4*)(Fh + (size_t)gB * 256) + kq;

      f32x16 acc;
#pragma unroll
      for (int q = 0; q < 16; ++q) acc[q] = 0.0f;
#pragma unroll
      for (int it = 0; it < 16; ++it) {
        const f16x8 a  = *(const f16x8*)&afr[it];
        const f16x8 bf = *(const f16x8*)(pB + 2 * it);
        acc = __builtin_amdgcn_mfma_f32_32x32x16_f16(a, bf, acc, 0, 0, 0);
      }

      // C/D: col = lane&31, row = (reg&3) + 8*(reg>>2) + 4*(lane>>5)
      const int ccs = ct * 32 + (lane & 31);
      if (ccs < Bc) {
#pragma unroll
        for (int reg = 0; reg < 16; ++reg) {
          const int row = (reg & 3) + 8 * (reg >> 2) + 4 * (lane >> 5);
          const int rrs = r0 + row;
          sims[row][ccs] = (rrs == ccs) ? -3.0e38f : acc[reg] * 10.0f;
        }
      }
    }
  }
  __syncthreads();

  // ---- phase 2: per-anchor losses (8 anchors per wave, serial) ----
  const int na = (Bc - r0) < SR ? (Bc - r0) : SR;
  const int n_pos = B - 1;
  const int n_neg = K - B;
  uint4* swv = sAr + wv * 32;

  for (int a8 = 0; a8 < 8; ++a8) {
    const int a = wv * 8 + a8;
    if (a >= na) break;
    const int i = g_bucket[bs + r0 + a];  // global anchor id

    // stage anchor row into wave-private LDS (in-order DS per wave)
    ((uint2*)swv)[lane] = ((const uint2*)(Fh + (size_t)i * 256))[lane];

    // sim row -> 5 registers (Bc <= 320)
    float v[5];
#pragma unroll
    for (int rr = 0; rr < 5; ++rr) {
      const int t = lane + rr * 64;
      v[rr] = (t < Bc) ? sims[a][t] : -3.4e38f;
    }

    int t6 = n_neg < MAXP ? n_neg : MAXP;
    if (t6 < 1) t6 = 1;
    int take = n_pos < t6 ? n_pos : t6;
    if (n_pos <= 0 || n_neg <= 0) take = 0;
    const int target = (take > 0) ? (n_neg < NEGK ? n_neg : NEGK) : 0;

    // ---- negatives: dual chains, all 16 row-chunks preloaded (MLP=16) ----
    const int s = lane & 3, g = lane >> 2;
    const int n0 = g, n1 = 16 + g;
    const uint64_t z0 = mix64(((uint64_t)(uint32_t)i << 32) | (uint32_t)n0);
    const uint64_t z1 = mix64(((uint64_t)(uint32_t)i << 32) | (uint32_t)n1);
    const unsigned int rr0 = (unsigned int)(((uint64_t)(uint32_t)z0 * (uint64_t)n_neg) >> 32);
    const unsigned int rr1 = (unsigned int)(((uint64_t)(uint32_t)z1 * (uint64_t)n_neg) >> 32);
    const int pos0 = (rr0 < (unsigned int)bs) ? (int)rr0 : (int)rr0 + B;
    const int pos1 = (rr1 < (unsigned int)bs) ? (int)rr1 : (int)rr1 + B;
    const bool pv0 = (n0 < target), pv1 = (n1 < target);
    const int j0 = pv0 ? g_bucket[pos0] : 0;
    const int j1 = pv1 ? g_bucket[pos1] : 0;
    const uint4* f0 = (const uint4*)(Fh + (size_t)j0 * 256);
    const uint4* f1 = (const uint4*)(Fh + (size_t)j1 * 256);
    uint4 c0a[8], c1a[8];
#pragma unroll
    for (int k = 0; k < 8; ++k) { c0a[k] = f0[k * 4 + s]; c1a[k] = f1[k * 4 + s]; }
    float d0 = 0.0f, d1 = 0.0f;
#pragma unroll
    for (int k = 0; k < 8; ++k) {
      const uint4 aw = swv[k * 4 + s];  // LDS 4-address multicast
      d0 = dot8h(c0a[k], aw, d0);
      d1 = dot8h(c1a[k], aw, d1);
    }
    d0 += __shfl_xor(d0, 1, 64); d0 += __shfl_xor(d0, 2, 64);
    d1 += __shfl_xor(d1, 1, 64); d1 += __shfl_xor(d1, 2, 64);
    float e = 0.0f;
    if (s == 0) {
      if (pv0) e += expf(d0 * 10.0f);
      if (pv1) e += expf(d1 * 10.0f);
    }
    const float wsum = wave_reduce_add(e);

    // ---- top-take positives: value-only max + exclude-by-equality ----
    float num = 0.0f;
    for (int r = 0; r < take; ++r) {
      float best = v[0];
#pragma unroll
      for (int c = 1; c < 5; ++c) best = fmaxf(best, v[c]);
#pragma unroll
      for (int o = 1; o < 64; o <<= 1) best = fmaxf(best, __shfl_xor(best, o, 64));
      num += expf(best);
#pragma unroll
      for (int c = 0; c < 5; ++c)
        if (v[c] == best) v[c] = -3.4e38f;
    }

    if (lane == 0) {
      float ls = 0.0f;
      if (take > 0) {
        const float denom = num + wsum;
        float ratio = denom > 0.0f ? num / denom : 0.0f;
        ratio = fmaxf(ratio, 1e-8f);
        ls = -logf(ratio);
      }
      g_part[i] = ls;                   // plain store, no atomics
    }
  }
}

// ---- reduce 8192 per-anchor losses -> mean ----
__global__ __launch_bounds__(1024) void k_final(const float* __restrict__ g_part,
                                                float* __restrict__ out, int K) {
  __shared__ float s[16];
  float p = 0.0f;
  for (int t = threadIdx.x; t < K; t += 1024) p += g_part[t];
  p = wave_reduce_add(p);
  if ((threadIdx.x & 63) == 0) s[threadIdx.x >> 6] = p;
  __syncthreads();
  if (threadIdx.x == 0) {
    float tot = 0.0f;
#pragma unroll
    for (int w = 0; w < 16; ++w) tot += s[w];
    out[0] = tot / (float)K;
  }
}

extern "C" void kernel_launch(void* const* d_in, const int* in_sizes, int n_in,
                              void* d_out, int out_size, void* d_ws, size_t ws_size,
                              hipStream_t stream) {
  (void)n_in; (void)out_size; (void)ws_size;
  const float* F = (const float*)d_in[0];
  const int* labels = (const int*)d_in[1];
  const int K = in_sizes[1];  // 8192; D=256 hard-assumed
  float* out = (float*)d_out;

  char* ws = (char*)d_ws;
  size_t off = 0;
  int*   g_start  = (int*)(ws + off);   off += 512;
  int*   g_bucket = (int*)(ws + off);   off += (size_t)K * 4;
  float* g_part   = (float*)(ws + off); off += (size_t)K * 4;
  off = (off + 255) & ~(size_t)255;
  __half* Fh      = (__half*)(ws + off); off += (size_t)K * 256 * 2;

  k_prep<<<K / 4 + 1, 256, 0, stream>>>(F, labels, K, Fh, g_start, g_bucket);
  {
    dim3 grid(64, (MAXBC + SR - 1) / SR);
    k_strip<<<grid, 256, 0, stream>>>(Fh, g_start, g_bucket, g_part, K);
  }
  k_final<<<1, 1024, 0, stream>>>(g_part, out, K);
}

// Round 6
// 116.571 us; speedup vs baseline: 1.0256x; 1.0256x over previous
//
#include <hip/hip_runtime.h>
#include <hip/hip_fp16.h>
#include <math.h>
#include <stdint.h>

// SupConLossTopK, K=8192, D=256, 64 labels, T=0.1, MAX_POS=6, NEG_K=30.
// Round 16 = round-15 strip fusion with the TLP fix: SR 32 -> 8.
//  - k_prep : normalize+bucket; bucket block moved to blockIdx 0 so its
//             ~6us serial chain overlaps the normalize blocks.
//  - k_strip: grid (64 x 40) ~= 1024 active blocks (r15: 256 = 1 block/CU,
//             8 serial anchors/wave -> ~30us, the r15 regression). Now:
//             12KB LDS, launch_bounds(256,4) -> 16 waves/CU, 2 serial
//             anchors/wave. Phase 1: 8-row strip as A-side of 32x32 MFMA
//             (rows 8..31 discarded; 4x MFMA waste ~ 0.3us chip-total;
//             4x B-panel re-reads = 64MB L2 ~ 2us, overlapped).
//  - k_final: separate 1-block mean (r13 lesson: same-line device-scope
//             arrivals cost ~33ns each; no fusion via single counter).
// No same-address global atomics anywhere (r4+r13 lessons).
// Harness floor inside dur_us: ~44us 0xAA poison of 256MiB ws + restore +
// graph node gaps (~5-6us x 6 boundaries at 7 dispatches/iter).
// exp(sim - rowmax) ratios == exp(sim) ratios -> no rowmax pass.

#define NEGK 30
#define MAXP 6
#define MAXBC 320   // max bucket rows (actual ~128 +-11; P(>320) ~ 1e-60)
#define SR 8        // strip rows (anchors per k_strip block)

typedef _Float16 h2v __attribute__((ext_vector_type(2)));
typedef _Float16 f16x8 __attribute__((ext_vector_type(8)));
typedef float f32x16 __attribute__((ext_vector_type(16)));

__device__ __forceinline__ uint64_t mix64(uint64_t z) {
  z += 0x9E3779B97F4A7C15ULL;
  z = (z ^ (z >> 30)) * 0xBF58476D1CE4E5B9ULL;
  z = (z ^ (z >> 27)) * 0x94D049BB133111EBULL;
  return z ^ (z >> 31);
}

__device__ __forceinline__ float wave_reduce_add(float p) {
#pragma unroll
  for (int o = 32; o; o >>= 1) p += __shfl_down(p, o, 64);
  return p;  // lane 0
}

// dot of 8 packed halfs (one 16B chunk) accumulated into acc
__device__ __forceinline__ float dot8h(uint4 a, uint4 b, float acc) {
  const h2v* pa = (const h2v*)&a;
  const h2v* pb = (const h2v*)&b;
#if __has_builtin(__builtin_amdgcn_fdot2)
#pragma unroll
  for (int q = 0; q < 4; ++q) acc = __builtin_amdgcn_fdot2(pa[q], pb[q], acc, false);
#else
#pragma unroll
  for (int q = 0; q < 4; ++q)
    acc += (float)pa[q].x * (float)pb[q].x + (float)pa[q].y * (float)pb[q].y;
#endif
  return acc;
}

// ---- fused: block 0 bucket-sorts; blocks 1..K/4 normalize rows -> fp16 ----
__global__ __launch_bounds__(256) void k_prep(const float* __restrict__ F,
                                              const int* __restrict__ labels, int K,
                                              __half* __restrict__ Fh,
                                              int* __restrict__ g_start,
                                              int* __restrict__ g_bucket) {
  __shared__ int cnt[64], start[65], cur[64];
  const int tid = threadIdx.x;

  if (blockIdx.x != 0) {
    const int row = (blockIdx.x - 1) * 4 + (tid >> 6);
    const int lane = tid & 63;
    const float4 a = ((const float4*)(F + (size_t)row * 256))[lane];
    float p = a.x * a.x + a.y * a.y + a.z * a.z + a.w * a.w;
    p = wave_reduce_add(p);
    p = __shfl(p, 0, 64);
    const float inv = 1.0f / fmaxf(sqrtf(p), 1e-12f);
    union { __half2 h[2]; uint2 u; } cv;
    cv.h[0] = __float22half2_rn(make_float2(a.x * inv, a.y * inv));
    cv.h[1] = __float22half2_rn(make_float2(a.z * inv, a.w * inv));
    ((uint2*)(Fh + (size_t)row * 256))[lane] = cv.u;
    return;
  }

  // bucket block (blockIdx 0: starts first, overlaps normalize blocks)
  if (tid < 64) cnt[tid] = 0;
  __syncthreads();
  for (int t = tid; t < K; t += 256) atomicAdd(&cnt[labels[t] & 63], 1);
  __syncthreads();
  if (tid == 0) {
    int acc = 0;
    for (int l = 0; l < 64; ++l) { start[l] = acc; acc += cnt[l]; }
    start[64] = acc;
  }
  __syncthreads();
  if (tid < 64) cur[tid] = start[tid];
  if (tid < 65) g_start[tid] = start[tid];
  __syncthreads();
  for (int t = tid; t < K; t += 256) {
    const int l = labels[t] & 63;
    const int p = atomicAdd(&cur[l], 1);
    g_bucket[p] = t;
  }
}

// ---- fused strip kernel: 8xBc Gram rows (MFMA, global-fed) -> LDS, then
// per-anchor loss for those 8 anchors. Grid (64, 40). No cross-block deps.
__global__ __launch_bounds__(256, 4) void k_strip(
    const __half* __restrict__ Fh, const int* __restrict__ g_start,
    const int* __restrict__ g_bucket, float* __restrict__ g_part, int K) {
  __shared__ float sims[SR][MAXBC];   // 8 x 320 x 4B = 10KB
  __shared__ uint4 sAr[4 * 32];       // 4 waves x 512B anchor staging

  const int b  = blockIdx.x;
  const int bs = g_start[b];
  const int B  = g_start[b + 1] - bs;
  const int Bc = B < MAXBC ? B : MAXBC;
  if (Bc <= 0) return;
  const int r0 = blockIdx.y * SR;
  if (r0 >= Bc) return;

  const int tid = threadIdx.x;
  const int wv = tid >> 6, lane = tid & 63;
  const int kq = lane >> 5;             // 0/1 -> +8 halfs within 16-half K-step

  // ---- phase 1: strip Gram rows via MFMA (global-fed fragments) ----
  // A-side: 32x32 MFMA but only strip rows 0..7 are kept (regs 0..3).
  {
    const int rA = r0 + (lane & 31);    // rows beyond strip: computed, unused
    const int gA = g_bucket[bs + (rA < Bc ? rA : Bc - 1)];
    const uint4* pA = (const uint4*)(Fh + (size_t)gA * 256) + kq;
    uint4 afr[16];
#pragma unroll
    for (int it = 0; it < 16; ++it) afr[it] = pA[2 * it];

    for (int ct = wv; ct * 32 < Bc; ct += 4) {
      const int rB = ct * 32 + (lane & 31);
      const int gB = g_bucket[bs + (rB < Bc ? rB : Bc - 1)];
      const uint4* pB = (const uint4*)(Fh + (size_t)gB * 256) + kq;

      f32x16 acc;
#pragma unroll
      for (int q = 0; q < 16; ++q) acc[q] = 0.0f;
#pragma unroll
      for (int it = 0; it < 16; ++it) {
        const f16x8 a  = *(const f16x8*)&afr[it];
        const f16x8 bf = *(const f16x8*)(pB + 2 * it);
        acc = __builtin_amdgcn_mfma_f32_32x32x16_f16(a, bf, acc, 0, 0, 0);
      }

      // C/D: col = lane&31, row = (reg&3) + 8*(reg>>2) + 4*(lane>>5).
      // Keep rows 0..7 -> regs 0..3 only.
      const int ccs = ct * 32 + (lane & 31);
      if (ccs < Bc) {
#pragma unroll
        for (int reg = 0; reg < 4; ++reg) {
          const int row = reg + 4 * kq;           // 0..7
          const int rrs = r0 + row;
          sims[row][ccs] = (rrs == ccs) ? -3.0e38f : acc[reg] * 10.0f;
        }
      }
    }
  }
  __syncthreads();

  // ---- phase 2: per-anchor losses (2 anchors per wave, serial) ----
  const int na = (Bc - r0) < SR ? (Bc - r0) : SR;
  const int n_pos = B - 1;
  const int n_neg = K - B;
  uint4* swv = sAr + wv * 32;

  for (int a2 = 0; a2 < 2; ++a2) {
    const int a = wv * 2 + a2;
    if (a >= na) break;
    const int i = g_bucket[bs + r0 + a];  // global anchor id

    // stage anchor row into wave-private LDS (in-order DS per wave)
    ((uint2*)swv)[lane] = ((const uint2*)(Fh + (size_t)i * 256))[lane];

    // sim row -> 5 registers (Bc <= 320)
    float v[5];
#pragma unroll
    for (int rr = 0; rr < 5; ++rr) {
      const int t = lane + rr * 64;
      v[rr] = (t < Bc) ? sims[a][t] : -3.4e38f;
    }

    int t6 = n_neg < MAXP ? n_neg : MAXP;
    if (t6 < 1) t6 = 1;
    int take = n_pos < t6 ? n_pos : t6;
    if (n_pos <= 0 || n_neg <= 0) take = 0;
    const int target = (take > 0) ? (n_neg < NEGK ? n_neg : NEGK) : 0;

    // ---- negatives: dual chains, all 16 row-chunks preloaded (MLP=16) ----
    const int s = lane & 3, g = lane >> 2;
    const int n0 = g, n1 = 16 + g;
    const uint64_t z0 = mix64(((uint64_t)(uint32_t)i << 32) | (uint32_t)n0);
    const uint64_t z1 = mix64(((uint64_t)(uint32_t)i << 32) | (uint32_t)n1);
    const unsigned int rr0 = (unsigned int)(((uint64_t)(uint32_t)z0 * (uint64_t)n_neg) >> 32);
    const unsigned int rr1 = (unsigned int)(((uint64_t)(uint32_t)z1 * (uint64_t)n_neg) >> 32);
    const int pos0 = (rr0 < (unsigned int)bs) ? (int)rr0 : (int)rr0 + B;
    const int pos1 = (rr1 < (unsigned int)bs) ? (int)rr1 : (int)rr1 + B;
    const bool pv0 = (n0 < target), pv1 = (n1 < target);
    const int j0 = pv0 ? g_bucket[pos0] : 0;
    const int j1 = pv1 ? g_bucket[pos1] : 0;
    const uint4* f0 = (const uint4*)(Fh + (size_t)j0 * 256);
    const uint4* f1 = (const uint4*)(Fh + (size_t)j1 * 256);
    uint4 c0a[8], c1a[8];
#pragma unroll
    for (int k = 0; k < 8; ++k) { c0a[k] = f0[k * 4 + s]; c1a[k] = f1[k * 4 + s]; }
    float d0 = 0.0f, d1 = 0.0f;
#pragma unroll
    for (int k = 0; k < 8; ++k) {
      const uint4 aw = swv[k * 4 + s];  // LDS 4-address multicast
      d0 = dot8h(c0a[k], aw, d0);
      d1 = dot8h(c1a[k], aw, d1);
    }
    d0 += __shfl_xor(d0, 1, 64); d0 += __shfl_xor(d0, 2, 64);
    d1 += __shfl_xor(d1, 1, 64); d1 += __shfl_xor(d1, 2, 64);
    float e = 0.0f;
    if (s == 0) {
      if (pv0) e += expf(d0 * 10.0f);
      if (pv1) e += expf(d1 * 10.0f);
    }
    const float wsum = wave_reduce_add(e);

    // ---- top-take positives: value-only max + exclude-by-equality ----
    float num = 0.0f;
    for (int r = 0; r < take; ++r) {
      float best = v[0];
#pragma unroll
      for (int c = 1; c < 5; ++c) best = fmaxf(best, v[c]);
#pragma unroll
      for (int o = 1; o < 64; o <<= 1) best = fmaxf(best, __shfl_xor(best, o, 64));
      num += expf(best);
#pragma unroll
      for (int c = 0; c < 5; ++c)
        if (v[c] == best) v[c] = -3.4e38f;
    }

    if (lane == 0) {
      float ls = 0.0f;
      if (take > 0) {
        const float denom = num + wsum;
        float ratio = denom > 0.0f ? num / denom : 0.0f;
        ratio = fmaxf(ratio, 1e-8f);
        ls = -logf(ratio);
      }
      g_part[i] = ls;                   // plain store, no atomics
    }
  }
}

// ---- reduce 8192 per-anchor losses -> mean ----
__global__ __launch_bounds__(1024) void k_final(const float* __restrict__ g_part,
                                                float* __restrict__ out, int K) {
  __shared__ float s[16];
  float p = 0.0f;
  for (int t = threadIdx.x; t < K; t += 1024) p += g_part[t];
  p = wave_reduce_add(p);
  if ((threadIdx.x & 63) == 0) s[threadIdx.x >> 6] = p;
  __syncthreads();
  if (threadIdx.x == 0) {
    float tot = 0.0f;
#pragma unroll
    for (int w = 0; w < 16; ++w) tot += s[w];
    out[0] = tot / (float)K;
  }
}

extern "C" void kernel_launch(void* const* d_in, const int* in_sizes, int n_in,
                              void* d_out, int out_size, void* d_ws, size_t ws_size,
                              hipStream_t stream) {
  (void)n_in; (void)out_size; (void)ws_size;
  const float* F = (const float*)d_in[0];
  const int* labels = (const int*)d_in[1];
  const int K = in_sizes[1];  // 8192; D=256 hard-assumed
  float* out = (float*)d_out;

  char* ws = (char*)d_ws;
  size_t off = 0;
  int*   g_start  = (int*)(ws + off);   off += 512;
  int*   g_bucket = (int*)(ws + off);   off += (size_t)K * 4;
  float* g_part   = (float*)(ws + off); off += (size_t)K * 4;
  off = (off + 255) & ~(size_t)255;
  __half* Fh      = (__half*)(ws + off); off += (size_t)K * 256 * 2;

  k_prep<<<K / 4 + 1, 256, 0, stream>>>(F, labels, K, Fh, g_start, g_bucket);
  {
    dim3 grid(64, (MAXBC + SR - 1) / SR);
    k_strip<<<grid, 256, 0, stream>>>(Fh, g_start, g_bucket, g_part, K);
  }
  k_final<<<1, 1024, 0, stream>>>(g_part, out, K);
}

// Round 7
// 104.533 us; speedup vs baseline: 1.1437x; 1.1152x over previous
//
#include <hip/hip_runtime.h>
#include <hip/hip_fp16.h>
#include <math.h>
#include <stdint.h>

// SupConLossTopK, K=8192, D=256, 64 labels, T=0.1, MAX_POS=6, NEG_K=30.
// Round 17 = revert to round-12 4-kernel structure (105.1us, best measured;
// fusions r13/r15/r16 all regressed) + two targeted changes:
//  - k_prep : bucket block moved to blockIdx 0 (its ~6us serial chain now
//             overlaps the normalize blocks).
//  - k_gram : EXACT round-12 staged-MFMA version (measured best).
//  - k_anchor: negative gathers regrouped 4->8 lanes per row (4 chains x
//             8 groups, slots n=c*8+g -> SAME mix64 draws as r9/r12,
//             bitwise-identical sums). Each load instruction now fetches
//             8 FULL 128B lines instead of 16 half-lines: 256 -> 128 L1
//             line-requests per wave. Theory: anchor body (~20us by r3
//             decomposition: 72us measured minus ~52us atomic tail) is
//             L1-line-request-rate bound (VALUBusy 9%, HBM ~0, occ 42%).
//  - k_final: unchanged.
// Lessons kept: no same-address global atomics (r4/r13); no device-scope
// arrive patterns (r13: ~33ns/arrival x 2048 = +52us); no gram+anchor
// fusion (r15/r16: +15us vs split).
// Harness floor inside dur_us: ~44us 0xAA poison of 256MiB ws + restore +
// ~7 inter-dispatch gaps.
// exp(sim - rowmax) ratios == exp(sim) ratios -> no rowmax pass.

#define NEGK 30
#define MAXP 6
#define MAXBC 320   // max bucket rows (actual ~128 +-11; P(>320) ~ 1e-60)
#define GT 64       // gram tile dim (64x64 per block)

typedef _Float16 h2v __attribute__((ext_vector_type(2)));
typedef _Float16 f16x8 __attribute__((ext_vector_type(8)));
typedef float f32x16 __attribute__((ext_vector_type(16)));

__device__ __forceinline__ uint64_t mix64(uint64_t z) {
  z += 0x9E3779B97F4A7C15ULL;
  z = (z ^ (z >> 30)) * 0xBF58476D1CE4E5B9ULL;
  z = (z ^ (z >> 27)) * 0x94D049BB133111EBULL;
  return z ^ (z >> 31);
}

__device__ __forceinline__ float wave_reduce_add(float p) {
#pragma unroll
  for (int o = 32; o; o >>= 1) p += __shfl_down(p, o, 64);
  return p;  // lane 0
}

// dot of 8 packed halfs (one 16B chunk) accumulated into acc
__device__ __forceinline__ float dot8h(uint4 a, uint4 b, float acc) {
  const h2v* pa = (const h2v*)&a;
  const h2v* pb = (const h2v*)&b;
#if __has_builtin(__builtin_amdgcn_fdot2)
#pragma unroll
  for (int q = 0; q < 4; ++q) acc = __builtin_amdgcn_fdot2(pa[q], pb[q], acc, false);
#else
#pragma unroll
  for (int q = 0; q < 4; ++q)
    acc += (float)pa[q].x * (float)pb[q].x + (float)pa[q].y * (float)pb[q].y;
#endif
  return acc;
}

// ---- fused: block 0 bucket-sorts; blocks 1..K/4 normalize rows -> fp16 ----
__global__ __launch_bounds__(256) void k_prep(const float* __restrict__ F,
                                              const int* __restrict__ labels, int K,
                                              __half* __restrict__ Fh,
                                              int* __restrict__ g_start,
                                              int* __restrict__ g_soff,
                                              int* __restrict__ g_bucket,
                                              int4* __restrict__ g_meta) {
  __shared__ int cnt[64], start[65], cur[64], soff_s[64];
  const int tid = threadIdx.x;

  if (blockIdx.x != 0) {
    const int row = (blockIdx.x - 1) * 4 + (tid >> 6);
    const int lane = tid & 63;
    const float4 a = ((const float4*)(F + (size_t)row * 256))[lane];
    float p = a.x * a.x + a.y * a.y + a.z * a.z + a.w * a.w;
    p = wave_reduce_add(p);
    p = __shfl(p, 0, 64);
    const float inv = 1.0f / fmaxf(sqrtf(p), 1e-12f);
    union { __half2 h[2]; uint2 u; } cv;
    cv.h[0] = __float22half2_rn(make_float2(a.x * inv, a.y * inv));
    cv.h[1] = __float22half2_rn(make_float2(a.z * inv, a.w * inv));
    ((uint2*)(Fh + (size_t)row * 256))[lane] = cv.u;
    return;
  }

  // bucket block (blockIdx 0: starts first, overlaps normalize blocks)
  if (tid < 64) cnt[tid] = 0;
  __syncthreads();
  for (int t = tid; t < K; t += 256) atomicAdd(&cnt[labels[t] & 63], 1);
  __syncthreads();
  if (tid == 0) {
    int acc = 0, sacc = 0;
    for (int l = 0; l < 64; ++l) {
      start[l] = acc;
      const int B = cnt[l];
      acc += B;
      soff_s[l] = sacc;
      const int Bc = B < MAXBC ? B : MAXBC;
      sacc += Bc * Bc;
    }
    start[64] = acc;
  }
  __syncthreads();
  if (tid < 64) { cur[tid] = start[tid]; g_soff[tid] = soff_s[tid]; }
  if (tid < 65) g_start[tid] = start[tid];
  __syncthreads();
  for (int t = tid; t < K; t += 256) {
    const int l = labels[t] & 63;
    const int p = atomicAdd(&cur[l], 1);
    g_bucket[p] = t;
    g_meta[t] = make_int4(start[l], cnt[l], p - start[l], soff_s[l]);
  }
}

// ---- per-bucket Gram (sim*10, diag=-3e38) via MFMA: 64x64 tiles ----
// (exact round-12 version — measured best)
__global__ __launch_bounds__(256) void k_gram(const __half* __restrict__ Fh,
                                              const int* __restrict__ g_start,
                                              const int* __restrict__ g_soff,
                                              const int* __restrict__ g_bucket,
                                              float* __restrict__ g_sims) {
  __shared__ uint4 sR[64 * 32];  // 64 row-rows   x 512B = 32KB
  __shared__ uint4 sC[64 * 32];  // 64 col-rows   x 512B = 32KB

  const int b  = blockIdx.x;
  const int bs = g_start[b];
  const int B  = g_start[b + 1] - bs;
  const int Bc = B < MAXBC ? B : MAXBC;
  if (Bc <= 0) return;  // defensive (empty bucket; unreachable in practice)
  const int r0 = blockIdx.y * GT;
  const int c0 = blockIdx.z * GT;
  if (r0 >= Bc || c0 >= Bc) return;
  const int tid = threadIdx.x;

  // stage 64 row-rows + 64 col-rows (clamped gather), swizzled chunk slots.
  for (int u = tid; u < 64 * 32; u += 256) {
    const int r = u >> 5, ch = u & 31;
    const int sl = ch ^ (r & 31);
    const int rr = r0 + r;
    const int gr = g_bucket[bs + (rr < Bc ? rr : Bc - 1)];
    sR[(r << 5) | sl] = ((const uint4*)(Fh + (size_t)gr * 256))[ch];
    const int cc = c0 + r;
    const int gc = g_bucket[bs + (cc < Bc ? cc : Bc - 1)];
    sC[(r << 5) | sl] = ((const uint4*)(Fh + (size_t)gc * 256))[ch];
  }
  __syncthreads();

  const int wv = tid >> 6, lane = tid & 63;
  const int wr = (wv >> 1) * 32;        // sub-tile row base (0/32)
  const int wc = (wv & 1) * 32;         // sub-tile col base (0/32)
  const int rA = wr + (lane & 31);      // block-local A row
  const int rB = wc + (lane & 31);      // block-local B row (gram column)
  const int kq = lane >> 5;             // 0/1 -> +8 halfs within 16-half K-step

  f32x16 acc;
#pragma unroll
  for (int q = 0; q < 16; ++q) acc[q] = 0.0f;

#pragma unroll
  for (int it = 0; it < 16; ++it) {
    const int slot = 2 * it + kq;
    const f16x8 a  = *(const f16x8*)&sR[(rA << 5) | (slot ^ (rA & 31))];
    const f16x8 bf = *(const f16x8*)&sC[(rB << 5) | (slot ^ (rB & 31))];
    acc = __builtin_amdgcn_mfma_f32_32x32x16_f16(a, bf, acc, 0, 0, 0);
  }

  // C/D layout (verified): col = lane&31, row = (reg&3) + 8*(reg>>2) + 4*(lane>>5)
  float* outb = g_sims + g_soff[b];
  const int ccs = c0 + wc + (lane & 31);
  const bool cok = ccs < Bc;
#pragma unroll
  for (int reg = 0; reg < 16; ++reg) {
    const int row = (reg & 3) + 8 * (reg >> 2) + 4 * (lane >> 5);
    const int rrs = r0 + wr + row;
    if (cok && rrs < Bc)
      outb[(size_t)rrs * Bc + ccs] = (rrs == ccs) ? -3.0e38f : acc[reg] * 10.0f;
  }
}

// ---- per-anchor: one wave; value-only argmax + quad-chain negatives ----
// Negative gathers: 8 lanes/row (s=lane&7), 8 groups, 4 chains; slots
// n=c*8+g == same 0..31 set as r9 -> bitwise-identical RNG draws. Each
// load instr now fetches 8 FULL 128B lines (was 16 half-lines): 2x fewer
// L1 line-requests.
__global__ __launch_bounds__(256) void k_anchor(
    const __half* __restrict__ Fh, const int* __restrict__ g_bucket,
    const int4* __restrict__ g_meta, const float* __restrict__ g_sims,
    float* __restrict__ g_part, int K) {
  __shared__ uint4 sA[4 * 32];        // 4 waves x 512B anchor rows
  const int wv = threadIdx.x >> 6;
  const int lane = threadIdx.x & 63;
  const int i = blockIdx.x * 4 + wv;  // K multiple of 4

  // stage anchor row into wave-private LDS (independent of meta)
  ((uint2*)sA)[wv * 64 + lane] = ((const uint2*)(Fh + (size_t)i * 256))[lane];
  const uint4* sw = sA + wv * 32;

  const int4 mt = g_meta[i];          // (bucket_start, bucket_size, loc, soff)
  const int bs = mt.x, B = mt.y;
  const int Bc = B < MAXBC ? B : MAXBC;
  int loc = mt.z;
  if (loc >= Bc) loc = 0;             // unreachable in practice
  const int n_pos = B - 1;
  const int n_neg = K - B;
  const float* simrow = g_sims + mt.w + (size_t)loc * Bc;

  // sim row -> 5 registers (Bc <= 320)
  float v[5];
#pragma unroll
  for (int rr = 0; rr < 5; ++rr) {
    const int t = lane + rr * 64;
    v[rr] = (t < Bc) ? simrow[t] : -3.4e38f;
  }

  int t6 = n_neg < MAXP ? n_neg : MAXP;
  if (t6 < 1) t6 = 1;
  int take = n_pos < t6 ? n_pos : t6;
  if (n_pos <= 0 || n_neg <= 0) take = 0;
  const int target = (take > 0) ? (n_neg < NEGK ? n_neg : NEGK) : 0;

  // ---- negatives first: 4 chains x 8 row-groups, full-line gathers ----
  const int s = lane & 7, g = lane >> 3;
  const int n0 = g, n1 = 8 + g, n2 = 16 + g, n3 = 24 + g;
  const uint64_t z0 = mix64(((uint64_t)(uint32_t)i << 32) | (uint32_t)n0);
  const uint64_t z1 = mix64(((uint64_t)(uint32_t)i << 32) | (uint32_t)n1);
  const uint64_t z2 = mix64(((uint64_t)(uint32_t)i << 32) | (uint32_t)n2);
  const uint64_t z3 = mix64(((uint64_t)(uint32_t)i << 32) | (uint32_t)n3);
  const unsigned int r0 = (unsigned int)(((uint64_t)(uint32_t)z0 * (uint64_t)n_neg) >> 32);
  const unsigned int r1 = (unsigned int)(((uint64_t)(uint32_t)z1 * (uint64_t)n_neg) >> 32);
  const unsigned int r2 = (unsigned int)(((uint64_t)(uint32_t)z2 * (uint64_t)n_neg) >> 32);
  const unsigned int r3 = (unsigned int)(((uint64_t)(uint32_t)z3 * (uint64_t)n_neg) >> 32);
  const int pos0 = (r0 < (unsigned int)bs) ? (int)r0 : (int)r0 + B;
  const int pos1 = (r1 < (unsigned int)bs) ? (int)r1 : (int)r1 + B;
  const int pos2 = (r2 < (unsigned int)bs) ? (int)r2 : (int)r2 + B;
  const int pos3 = (r3 < (unsigned int)bs) ? (int)r3 : (int)r3 + B;
  const bool pv0 = (n0 < target), pv1 = (n1 < target);
  const bool pv2 = (n2 < target), pv3 = (n3 < target);
  const int j0 = pv0 ? g_bucket[pos0] : 0;
  const int j1 = pv1 ? g_bucket[pos1] : 0;
  const int j2 = pv2 ? g_bucket[pos2] : 0;
  const int j3 = pv3 ? g_bucket[pos3] : 0;
  const uint4* f0 = (const uint4*)(Fh + (size_t)j0 * 256);
  const uint4* f1 = (const uint4*)(Fh + (size_t)j1 * 256);
  const uint4* f2 = (const uint4*)(Fh + (size_t)j2 * 256);
  const uint4* f3 = (const uint4*)(Fh + (size_t)j3 * 256);
  float d0 = 0.0f, d1 = 0.0f, d2 = 0.0f, d3 = 0.0f;
#pragma unroll
  for (int k = 0; k < 4; ++k) {
    const int ch = k * 8 + s;         // lane's 16B chunk within the 128B line k
    const uint4 aw = sw[ch];          // LDS multicast (8 distinct uint4 -> 32 banks)
    d0 = dot8h(f0[ch], aw, d0);
    d1 = dot8h(f1[ch], aw, d1);
    d2 = dot8h(f2[ch], aw, d2);
    d3 = dot8h(f3[ch], aw, d3);
  }
  d0 += __shfl_xor(d0, 1, 64); d0 += __shfl_xor(d0, 2, 64); d0 += __shfl_xor(d0, 4, 64);
  d1 += __shfl_xor(d1, 1, 64); d1 += __shfl_xor(d1, 2, 64); d1 += __shfl_xor(d1, 4, 64);
  d2 += __shfl_xor(d2, 1, 64); d2 += __shfl_xor(d2, 2, 64); d2 += __shfl_xor(d2, 4, 64);
  d3 += __shfl_xor(d3, 1, 64); d3 += __shfl_xor(d3, 2, 64); d3 += __shfl_xor(d3, 4, 64);
  float e = 0.0f;
  if (s == 0) {
    if (pv0) e += expf(d0 * 10.0f);
    if (pv1) e += expf(d1 * 10.0f);
    if (pv2) e += expf(d2 * 10.0f);
    if (pv3) e += expf(d3 * 10.0f);
  }
  const float wsum = wave_reduce_add(e);

  // ---- top-take positives: value-only max + exclude-by-equality ----
  float num = 0.0f;
  for (int r = 0; r < take; ++r) {
    float best = v[0];
#pragma unroll
    for (int c = 1; c < 5; ++c) best = fmaxf(best, v[c]);
#pragma unroll
    for (int o = 1; o < 64; o <<= 1) best = fmaxf(best, __shfl_xor(best, o, 64));
    num += expf(best);
#pragma unroll
    for (int c = 0; c < 5; ++c)
      if (v[c] == best) v[c] = -3.4e38f;
  }

  if (lane == 0) {
    float ls = 0.0f;
    if (take > 0) {
      const float denom = num + wsum;
      float ratio = denom > 0.0f ? num / denom : 0.0f;
      ratio = fmaxf(ratio, 1e-8f);
      ls = -logf(ratio);
    }
    g_part[i] = ls;                   // plain store, no atomics
  }
}

// ---- reduce 8192 per-anchor losses -> mean ----
__global__ __launch_bounds__(1024) void k_final(const float* __restrict__ g_part,
                                                float* __restrict__ out, int K) {
  __shared__ float s[16];
  float p = 0.0f;
  for (int t = threadIdx.x; t < K; t += 1024) p += g_part[t];
  p = wave_reduce_add(p);
  if ((threadIdx.x & 63) == 0) s[threadIdx.x >> 6] = p;
  __syncthreads();
  if (threadIdx.x == 0) {
    float tot = 0.0f;
#pragma unroll
    for (int w = 0; w < 16; ++w) tot += s[w];
    out[0] = tot / (float)K;
  }
}

extern "C" void kernel_launch(void* const* d_in, const int* in_sizes, int n_in,
                              void* d_out, int out_size, void* d_ws, size_t ws_size,
                              hipStream_t stream) {
  (void)n_in; (void)out_size; (void)ws_size;
  const float* F = (const float*)d_in[0];
  const int* labels = (const int*)d_in[1];
  const int K = in_sizes[1];  // 8192; D=256 hard-assumed
  float* out = (float*)d_out;

  char* ws = (char*)d_ws;
  size_t off = 0;
  int*   g_start  = (int*)(ws + off);   off += 512;
  int*   g_soff   = (int*)(ws + off);   off += 256;
  int*   g_bucket = (int*)(ws + off);   off += (size_t)K * 4;
  float* g_part   = (float*)(ws + off); off += (size_t)K * 4;
  off = (off + 255) & ~(size_t)255;
  int4*  g_meta   = (int4*)(ws + off);  off += (size_t)K * 16;
  __half* Fh      = (__half*)(ws + off); off += (size_t)K * 256 * 2;
  float* g_sims   = (float*)(ws + off);  off += (size_t)MAXBC * K * 4;

  k_prep<<<K / 4 + 1, 256, 0, stream>>>(F, labels, K, Fh, g_start, g_soff,
                                        g_bucket, g_meta);
  {
    dim3 grid(64, (MAXBC + GT - 1) / GT, (MAXBC + GT - 1) / GT);
    k_gram<<<grid, 256, 0, stream>>>(Fh, g_start, g_soff, g_bucket, g_sims);
  }
  k_anchor<<<K / 4, 256, 0, stream>>>(Fh, g_bucket, g_meta, g_sims, g_part, K);
  k_final<<<1, 1024, 0, stream>>>(g_part, out, K);
}